// Round 5
// baseline (2124.713 us; speedup 1.0000x reference)
//
#include <hip/hip_runtime.h>

typedef _Float16 half2_t __attribute__((ext_vector_type(2)));

#define BB 16
#define TT 4096
#define DD 128
#define HH 256

__device__ __forceinline__ float tanh_fast(float x) {
    // tanh(x) = 1 - 2/(exp(2x)+1); exact at both saturations
    float e = __expf(2.0f * x);
    return 1.0f - 2.0f * __builtin_amdgcn_rcpf(e + 1.0f);
}

// cross-lane: xor1/xor2 via DPP quad_perm (VALU pipe), xor4 via ds_swizzle
__device__ __forceinline__ float dpp_xor1(float a) {
    return __builtin_bit_cast(float, __builtin_amdgcn_mov_dpp(
        __builtin_bit_cast(int, a), 0xB1, 0xF, 0xF, true));  // quad_perm [1,0,3,2]
}
__device__ __forceinline__ float dpp_xor2(float a) {
    return __builtin_bit_cast(float, __builtin_amdgcn_mov_dpp(
        __builtin_bit_cast(int, a), 0x4E, 0xF, 0xF, true));  // quad_perm [2,3,0,1]
}
__device__ __forceinline__ float swz_xor4(float a) {
    return __builtin_bit_cast(float, __builtin_amdgcn_ds_swizzle(
        __builtin_bit_cast(int, a), 0x101F));                // lane ^= 4
}

// ---------------- Phase 1: xh[b,t,h] = sum_d X[b,t,d]*W_x[h,d] + b_x[h] -----
__global__ __launch_bounds__(256) void x2h_gemm(
    const float* __restrict__ inp, const float* __restrict__ Wx,
    const float* __restrict__ bx, float* __restrict__ out)
{
    const int tid = threadIdx.x;
    const int ty = tid >> 4, tx = tid & 15;
    const int row0 = blockIdx.x * 128 + ty * 8;   // flattened (b,t)
    const int col0 = blockIdx.y * 128 + tx * 8;   // h

    float acc[8][8] = {};

    #pragma unroll 2
    for (int k4 = 0; k4 < DD / 4; ++k4) {
        float4 a[8], b[8];
        #pragma unroll
        for (int r = 0; r < 8; ++r)
            a[r] = *(const float4*)&inp[(size_t)(row0 + r) * DD + k4 * 4];
        #pragma unroll
        for (int c = 0; c < 8; ++c)
            b[c] = *(const float4*)&Wx[(size_t)(col0 + c) * DD + k4 * 4];
        #pragma unroll
        for (int r = 0; r < 8; ++r)
            #pragma unroll
            for (int c = 0; c < 8; ++c)
                acc[r][c] += a[r].x * b[c].x + a[r].y * b[c].y
                           + a[r].z * b[c].z + a[r].w * b[c].w;
    }

    float4 bx0 = *(const float4*)&bx[col0];
    float4 bx1 = *(const float4*)&bx[col0 + 4];
    #pragma unroll
    for (int r = 0; r < 8; ++r) {
        float4 o0, o1;
        o0.x = acc[r][0] + bx0.x; o0.y = acc[r][1] + bx0.y;
        o0.z = acc[r][2] + bx0.z; o0.w = acc[r][3] + bx0.w;
        o1.x = acc[r][4] + bx1.x; o1.y = acc[r][5] + bx1.y;
        o1.z = acc[r][6] + bx1.z; o1.w = acc[r][7] + bx1.w;
        *(float4*)&out[(size_t)(row0 + r) * HH + col0]     = o0;
        *(float4*)&out[(size_t)(row0 + r) * HH + col0 + 4] = o1;
    }
}

// ---------------- Phase 2: sequential scan, 512 threads per batch -----------
// Same structure as R4 (8 waves; lane l: o=l>>3, r=l&7; 4 outputs {4o+s} over
// K-chunk h[32r..32r+32); derotated reads; DPP/swizzle butterfly) BUT the 64
// weight half2 values are 64 INDIVIDUALLY-NAMED scalars instead of an array:
// R2-R4 showed the compiler places weight ARRAYS in AGPRs (VGPR_Count 76 vs
// the ~115 needed), and fdot2 can't source AGPRs -> one v_accvgpr_read per
// fdot2, doubling VALU issue (measured 63% active-CU VALUBusy vs ~31% floor).
// Named scalars with all-literal uses allocate as arch VGPRs.
__global__ __launch_bounds__(512, 2) void rnn_scan(
    const float* __restrict__ Wh, const float* __restrict__ bh,
    float* __restrict__ out)
{
    const int l = threadIdx.x;          // 0..511
    const int o = l >> 3;               // 0..63  output base group
    const int r = l & 7;                // 0..7   K-chunk
    const int b = blockIdx.x;           // batch
    const int jf = (o << 2) + (r & 3);  // finalized output unit (lanes r<4)

    __shared__ __align__(16) _Float16 hA[HH];
    __shared__ __align__(16) _Float16 hB[HH];

    // derotated LDS byte offsets: chunk base r*64B, sub-slot (q+r)&3
    int ldoff[4];
    #pragma unroll
    for (int q = 0; q < 4; ++q)
        ldoff[q] = (r << 6) + (((q + r) & 3) << 4);

    // 64 named weight half2 scalars: w_S_Q_M covers logical cols
    // 32r + 8*((Q+r)&3) + {2M,2M+1} of row 4o+S
#define DECLQ(S,Q) half2_t w_##S##_##Q##_0, w_##S##_##Q##_1, w_##S##_##Q##_2, w_##S##_##Q##_3;
#define DECLS(S) DECLQ(S,0) DECLQ(S,1) DECLQ(S,2) DECLQ(S,3)
    DECLS(0) DECLS(1) DECLS(2) DECLS(3)
#undef DECLS
#undef DECLQ

#define WLOADQ(S,Q)                                                            \
    {                                                                          \
        int qq = ((Q) + r) & 3;                                                \
        const float* wp = Wh + (size_t)((o << 2) + (S)) * HH + (r << 5) + qq * 8; \
        float4 v0 = *(const float4*)wp;                                        \
        float4 v1 = *(const float4*)(wp + 4);                                  \
        w_##S##_##Q##_0 = half2_t{(_Float16)v0.x, (_Float16)v0.y};             \
        w_##S##_##Q##_1 = half2_t{(_Float16)v0.z, (_Float16)v0.w};             \
        w_##S##_##Q##_2 = half2_t{(_Float16)v1.x, (_Float16)v1.y};             \
        w_##S##_##Q##_3 = half2_t{(_Float16)v1.z, (_Float16)v1.w};             \
    }
    WLOADQ(0,0) WLOADQ(0,1) WLOADQ(0,2) WLOADQ(0,3)
    WLOADQ(1,0) WLOADQ(1,1) WLOADQ(1,2) WLOADQ(1,3)
    WLOADQ(2,0) WLOADQ(2,1) WLOADQ(2,2) WLOADQ(2,3)
    WLOADQ(3,0) WLOADQ(3,1) WLOADQ(3,2) WLOADQ(3,3)
#undef WLOADQ

    const float bhv = bh[jf];
    if (l < HH) hA[l] = (_Float16)0.f;

    float* colp = out + (size_t)b * TT * HH + jf;   // xh column jf, stride HH

    constexpr int CH = 8;                           // prefetch chunk (timesteps)
    float xc[CH], xn[CH];
    #pragma unroll
    for (int i = 0; i < CH; ++i) xc[i] = colp[(size_t)i * HH];
    __syncthreads();   // hA (zeros) visible

    const bool s1 = (r & 1) != 0, s2 = (r & 2) != 0;

#define QBLK(HV, QI)                                                           \
    {                                                                          \
        half2_t h0 = __builtin_bit_cast(half2_t, (HV).x);                      \
        half2_t h1 = __builtin_bit_cast(half2_t, (HV).y);                      \
        half2_t h2 = __builtin_bit_cast(half2_t, (HV).z);                      \
        half2_t h3 = __builtin_bit_cast(half2_t, (HV).w);                      \
        a0 = __builtin_amdgcn_fdot2(h0, w_0_##QI##_0, a0, false);              \
        a0 = __builtin_amdgcn_fdot2(h1, w_0_##QI##_1, a0, false);              \
        a0 = __builtin_amdgcn_fdot2(h2, w_0_##QI##_2, a0, false);              \
        a0 = __builtin_amdgcn_fdot2(h3, w_0_##QI##_3, a0, false);              \
        a1 = __builtin_amdgcn_fdot2(h0, w_1_##QI##_0, a1, false);              \
        a1 = __builtin_amdgcn_fdot2(h1, w_1_##QI##_1, a1, false);              \
        a1 = __builtin_amdgcn_fdot2(h2, w_1_##QI##_2, a1, false);              \
        a1 = __builtin_amdgcn_fdot2(h3, w_1_##QI##_3, a1, false);              \
        a2 = __builtin_amdgcn_fdot2(h0, w_2_##QI##_0, a2, false);              \
        a2 = __builtin_amdgcn_fdot2(h1, w_2_##QI##_1, a2, false);              \
        a2 = __builtin_amdgcn_fdot2(h2, w_2_##QI##_2, a2, false);              \
        a2 = __builtin_amdgcn_fdot2(h3, w_2_##QI##_3, a2, false);              \
        a3 = __builtin_amdgcn_fdot2(h0, w_3_##QI##_0, a3, false);              \
        a3 = __builtin_amdgcn_fdot2(h1, w_3_##QI##_1, a3, false);              \
        a3 = __builtin_amdgcn_fdot2(h2, w_3_##QI##_2, a3, false);              \
        a3 = __builtin_amdgcn_fdot2(h3, w_3_##QI##_3, a3, false);              \
    }

#define DOT_STEP(SRC, DST, XV, OPTR)                                           \
    {                                                                          \
        const char* hbase = (const char*)(SRC);                                \
        uint4 hv0 = *(const uint4*)(hbase + ldoff[0]);                         \
        uint4 hv1 = *(const uint4*)(hbase + ldoff[1]);                         \
        uint4 hv2 = *(const uint4*)(hbase + ldoff[2]);                         \
        uint4 hv3 = *(const uint4*)(hbase + ldoff[3]);                         \
        float a0 = 0.f, a1 = 0.f, a2 = 0.f, a3 = 0.f;                          \
        QBLK(hv0, 0) QBLK(hv1, 1) QBLK(hv2, 2) QBLK(hv3, 3)                    \
        /* stage 1 (xor1): keep s with s&1 == r&1 */                           \
        float b0, b1, c0, tk, ts;                                              \
        tk = s1 ? a1 : a0; ts = s1 ? a0 : a1; b0 = tk + dpp_xor1(ts);          \
        tk = s1 ? a3 : a2; ts = s1 ? a2 : a3; b1 = tk + dpp_xor1(ts);          \
        /* stage 2 (xor2): keep s with s&2 == r&2 */                           \
        tk = s2 ? b1 : b0; ts = s2 ? b0 : b1; c0 = tk + dpp_xor2(ts);          \
        /* stage 3 (xor4): partners share s -> plain K-completion add */       \
        float av = c0 + swz_xor4(c0);                                          \
        float z  = (XV) + bhv + av;                                            \
        float hn = tanh_fast(z);                                               \
        if (r < 4) {                                                           \
            *(OPTR) = hn;                                                      \
            (DST)[jf] = (_Float16)hn;                                          \
        }                                                                      \
    }                                                                          \
    __syncthreads();

    const int NC = TT / CH;
    for (int c = 0; c < NC; ++c) {
        if (c + 1 < NC) {
            const float* p = colp + (size_t)(c + 1) * CH * HH;
            #pragma unroll
            for (int i = 0; i < CH; ++i) xn[i] = p[(size_t)i * HH];
        }
        float* op = colp + (size_t)c * CH * HH;
        #pragma unroll
        for (int s = 0; s < CH; s += 2) {
            DOT_STEP(hA, hB, xc[s],     op + (size_t)s * HH)
            DOT_STEP(hB, hA, xc[s + 1], op + (size_t)(s + 1) * HH)
        }
        #pragma unroll
        for (int i = 0; i < CH; ++i) xc[i] = xn[i];
    }
#undef DOT_STEP
#undef QBLK
}

extern "C" void kernel_launch(void* const* d_in, const int* in_sizes, int n_in,
                              void* d_out, int out_size, void* d_ws, size_t ws_size,
                              hipStream_t stream) {
    const float* inp = (const float*)d_in[0];   // [B,T,D]
    const float* Wx  = (const float*)d_in[1];   // [H,D]
    const float* bx  = (const float*)d_in[2];   // [H]
    const float* Wh  = (const float*)d_in[3];   // [H,H]
    const float* bh  = (const float*)d_in[4];   // [H]
    float* out = (float*)d_out;                 // [B,T,H]

    dim3 g1(BB * TT / 128, HH / 128);
    x2h_gemm<<<g1, 256, 0, stream>>>(inp, Wx, bx, out);
    rnn_scan<<<BB, 512, 0, stream>>>(Wh, bh, out);
}

// Round 7
// 1793.250 us; speedup vs baseline: 1.1848x; 1.1848x over previous
//
#include <hip/hip_runtime.h>

typedef _Float16 f16x8 __attribute__((ext_vector_type(8)));
typedef float f32x4 __attribute__((ext_vector_type(4)));

#define BB 16
#define TT 4096
#define DD 128
#define HH 256

__device__ __forceinline__ float tanh_fast(float x) {
    // tanh(x) = 1 - 2/(exp(2x)+1); exact at both saturations
    float e = __expf(2.0f * x);
    return 1.0f - 2.0f * __builtin_amdgcn_rcpf(e + 1.0f);
}

// ---------------- Phase 1: xh[b,t,h] = sum_d X[b,t,d]*W_x[h,d] + b_x[h] -----
__global__ __launch_bounds__(256) void x2h_gemm(
    const float* __restrict__ inp, const float* __restrict__ Wx,
    const float* __restrict__ bx, float* __restrict__ out)
{
    const int tid = threadIdx.x;
    const int ty = tid >> 4, tx = tid & 15;
    const int row0 = blockIdx.x * 128 + ty * 8;   // flattened (b,t)
    const int col0 = blockIdx.y * 128 + tx * 8;   // h

    float acc[8][8] = {};

    #pragma unroll 2
    for (int k4 = 0; k4 < DD / 4; ++k4) {
        float4 a[8], b[8];
        #pragma unroll
        for (int r = 0; r < 8; ++r)
            a[r] = *(const float4*)&inp[(size_t)(row0 + r) * DD + k4 * 4];
        #pragma unroll
        for (int c = 0; c < 8; ++c)
            b[c] = *(const float4*)&Wx[(size_t)(col0 + c) * DD + k4 * 4];
        #pragma unroll
        for (int r = 0; r < 8; ++r)
            #pragma unroll
            for (int c = 0; c < 8; ++c)
                acc[r][c] += a[r].x * b[c].x + a[r].y * b[c].y
                           + a[r].z * b[c].z + a[r].w * b[c].w;
    }

    float4 bx0 = *(const float4*)&bx[col0];
    float4 bx1 = *(const float4*)&bx[col0 + 4];
    #pragma unroll
    for (int r = 0; r < 8; ++r) {
        float4 o0, o1;
        o0.x = acc[r][0] + bx0.x; o0.y = acc[r][1] + bx0.y;
        o0.z = acc[r][2] + bx0.z; o0.w = acc[r][3] + bx0.w;
        o1.x = acc[r][4] + bx1.x; o1.y = acc[r][5] + bx1.y;
        o1.z = acc[r][6] + bx1.z; o1.w = acc[r][7] + bx1.w;
        *(float4*)&out[(size_t)(row0 + r) * HH + col0]     = o0;
        *(float4*)&out[(size_t)(row0 + r) * HH + col0 + 4] = o1;
    }
}

// ---------------- Phase 2: MFMA scan, one workgroup (4 waves) per batch -----
// h_t (1x256) x W_h^T (256x256) per step via mfma_f32_16x16x32_f16 with the
// M dimension broadcast: A[i][k] = h[k] for all i -> every C row equals the
// matvec result. Weights live as 128 AGPRs of B-fragments per lane (MFMA
// sources AGPRs natively -- no per-MAC accvgpr_read tax like R2-R5's fdot2).
// Wave w owns output cols [64w,64w+64): 4 N-tiles x 8 K-tiles = 32 MFMA/step.
// A-frags: 8 x ds_read_b128 from the 512B h buffer (4 distinct 16B lines per
// instr, 16-lane broadcast groups -> conflict-free). Lane owns j = 64w+lane
// (tile g=lane>>4, col lane&15); all C rows identical -> reg 0, cndmask by g.
__global__ __launch_bounds__(256, 1) void rnn_scan(
    const float* __restrict__ Wh, const float* __restrict__ bh,
    float* __restrict__ out)
{
    const int tid  = threadIdx.x;       // 0..255
    const int w    = tid >> 6;          // wave 0..3
    const int lane = tid & 63;
    const int g    = lane >> 4;         // k-group / owning tile 0..3
    const int c    = lane & 15;         // col within tile
    const int b    = blockIdx.x;        // batch
    const int j    = (w << 6) + lane;   // owned output unit

    __shared__ __align__(16) _Float16 hbuf[2][HH];

    // B-fragments (weights), resident for the whole scan:
    // wb[T][t] lane part = W[64w+16T+c][32t+8g .. +7] as 8 halfs
    f16x8 wb[4][8];
    #pragma unroll
    for (int T = 0; T < 4; ++T) {
        const float* wrow = Wh + (size_t)((w << 6) + (T << 4) + c) * HH;
        #pragma unroll
        for (int t = 0; t < 8; ++t) {
            const float* wp = wrow + (t << 5) + (g << 3);
            float4 v0 = *(const float4*)wp;
            float4 v1 = *(const float4*)(wp + 4);
            wb[T][t] = f16x8{(_Float16)v0.x, (_Float16)v0.y,
                             (_Float16)v0.z, (_Float16)v0.w,
                             (_Float16)v1.x, (_Float16)v1.y,
                             (_Float16)v1.z, (_Float16)v1.w};
        }
    }
    const float bhv = bh[j];
    hbuf[0][tid] = (_Float16)0.f;       // 256 threads cover all 256 units

    float* colp = out + (size_t)b * TT * HH + j;   // xh column j, stride HH

    constexpr int CH = 8;                           // x prefetch chunk
    float xc[CH], xn[CH];
    #pragma unroll
    for (int i = 0; i < CH; ++i) xc[i] = colp[(size_t)i * HH];
    __syncthreads();   // zeros visible

    const int abase = (g << 4);         // byte offset of this k-group's 16B

    int cur = 0;
    const int NC = TT / CH;
    for (int cch = 0; cch < NC; ++cch) {
        if (cch + 1 < NC) {
            const float* p = colp + (size_t)(cch + 1) * CH * HH;
            #pragma unroll
            for (int i = 0; i < CH; ++i) xn[i] = p[(size_t)i * HH];
        }
        float* op = colp + (size_t)cch * CH * HH;
        #pragma unroll
        for (int s = 0; s < CH; ++s) {
            const char* hb = (const char*)hbuf[cur];
            // A-fragments: h[32t+8g .. +7] per K-tile t (broadcast over M rows)
            uint4 hv0 = *(const uint4*)(hb + 0 * 64 + abase);
            uint4 hv1 = *(const uint4*)(hb + 1 * 64 + abase);
            uint4 hv2 = *(const uint4*)(hb + 2 * 64 + abase);
            uint4 hv3 = *(const uint4*)(hb + 3 * 64 + abase);
            uint4 hv4 = *(const uint4*)(hb + 4 * 64 + abase);
            uint4 hv5 = *(const uint4*)(hb + 5 * 64 + abase);
            uint4 hv6 = *(const uint4*)(hb + 6 * 64 + abase);
            uint4 hv7 = *(const uint4*)(hb + 7 * 64 + abase);
            f16x8 a0 = __builtin_bit_cast(f16x8, hv0);
            f16x8 a1 = __builtin_bit_cast(f16x8, hv1);
            f16x8 a2 = __builtin_bit_cast(f16x8, hv2);
            f16x8 a3 = __builtin_bit_cast(f16x8, hv3);
            f16x8 a4 = __builtin_bit_cast(f16x8, hv4);
            f16x8 a5 = __builtin_bit_cast(f16x8, hv5);
            f16x8 a6 = __builtin_bit_cast(f16x8, hv6);
            f16x8 a7 = __builtin_bit_cast(f16x8, hv7);

            f32x4 acc0 = {0.f, 0.f, 0.f, 0.f};
            f32x4 acc1 = {0.f, 0.f, 0.f, 0.f};
            f32x4 acc2 = {0.f, 0.f, 0.f, 0.f};
            f32x4 acc3 = {0.f, 0.f, 0.f, 0.f};
#define MF(ACC, T, AV, TI) \
            ACC = __builtin_amdgcn_mfma_f32_16x16x32_f16(AV, wb[T][TI], ACC, 0, 0, 0);
            MF(acc0, 0, a0, 0) MF(acc1, 1, a0, 0) MF(acc2, 2, a0, 0) MF(acc3, 3, a0, 0)
            MF(acc0, 0, a1, 1) MF(acc1, 1, a1, 1) MF(acc2, 2, a1, 1) MF(acc3, 3, a1, 1)
            MF(acc0, 0, a2, 2) MF(acc1, 1, a2, 2) MF(acc2, 2, a2, 2) MF(acc3, 3, a2, 2)
            MF(acc0, 0, a3, 3) MF(acc1, 1, a3, 3) MF(acc2, 2, a3, 3) MF(acc3, 3, a3, 3)
            MF(acc0, 0, a4, 4) MF(acc1, 1, a4, 4) MF(acc2, 2, a4, 4) MF(acc3, 3, a4, 4)
            MF(acc0, 0, a5, 5) MF(acc1, 1, a5, 5) MF(acc2, 2, a5, 5) MF(acc3, 3, a5, 5)
            MF(acc0, 0, a6, 6) MF(acc1, 1, a6, 6) MF(acc2, 2, a6, 6) MF(acc3, 3, a6, 6)
            MF(acc0, 0, a7, 7) MF(acc1, 1, a7, 7) MF(acc2, 2, a7, 7) MF(acc3, 3, a7, 7)
#undef MF
            // lane owns tile g, col c; all C rows identical -> element 0
            float av = acc0[0];
            av = (g == 1) ? acc1[0] : av;
            av = (g == 2) ? acc2[0] : av;
            av = (g == 3) ? acc3[0] : av;

            float z  = xc[s] + bhv + av;
            float hn = tanh_fast(z);
            op[(size_t)s * HH] = hn;                 // overwrite xh with h
            hbuf[cur ^ 1][j] = (_Float16)hn;         // publish for next step
            cur ^= 1;
            __syncthreads();
        }
        #pragma unroll
        for (int i = 0; i < CH; ++i) xc[i] = xn[i];
    }
}

extern "C" void kernel_launch(void* const* d_in, const int* in_sizes, int n_in,
                              void* d_out, int out_size, void* d_ws, size_t ws_size,
                              hipStream_t stream) {
    const float* inp = (const float*)d_in[0];   // [B,T,D]
    const float* Wx  = (const float*)d_in[1];   // [H,D]
    const float* bx  = (const float*)d_in[2];   // [H]
    const float* Wh  = (const float*)d_in[3];   // [H,H]
    const float* bh  = (const float*)d_in[4];   // [H]
    float* out = (float*)d_out;                 // [B,T,H]

    dim3 g1(BB * TT / 128, HH / 128);
    x2h_gemm<<<g1, 256, 0, stream>>>(inp, Wx, bx, out);
    rnn_scan<<<BB, 256, 0, stream>>>(Wh, bh, out);
}